// Round 6
// baseline (15720.732 us; speedup 1.0000x reference)
//
#include <hip/hip_runtime.h>
#include <cstdint>
#include <cstddef>

#define B_   32
#define T_   2048
#define OBS_ 64
#define FC_  256
#define ACT_ 100
#define H_   512
#define TC_  128
#define NCH_ 16

typedef __attribute__((ext_vector_type(4))) unsigned int u32x4;
typedef __attribute__((ext_vector_type(8))) short bf16x8;
typedef __attribute__((ext_vector_type(4))) float f32x4;

static __device__ __forceinline__ bf16x8 as_b(u32x4 v){ union{u32x4 u; bf16x8 b;} x; x.u=v; return x.b; }
static __device__ __forceinline__ unsigned short f2bf(float f){
  unsigned int u = __builtin_bit_cast(unsigned int, f);
  return (unsigned short)((u + 0x7fffu + ((u>>16)&1u)) >> 16);
}
static __device__ __forceinline__ float bf2f(unsigned short s){
  unsigned int u = ((unsigned int)s) << 16;
  return __builtin_bit_cast(float, u);
}
static __device__ __forceinline__ void split3(float v, unsigned short& h, unsigned short& m, unsigned short& l){
  h = f2bf(v);
  float r1 = v - bf2f(h);
  m = f2bf(r1);
  float r2 = r1 - bf2f(m);
  l = f2bf(r2);
}
static __device__ __forceinline__ u32x4 pack8(const unsigned short* v){
  u32x4 r;
  r.x = (unsigned)v[0] | ((unsigned)v[1]<<16);
  r.y = (unsigned)v[2] | ((unsigned)v[3]<<16);
  r.z = (unsigned)v[4] | ((unsigned)v[5]<<16);
  r.w = (unsigned)v[6] | ((unsigned)v[7]<<16);
  return r;
}
// agent-coherent 16B load (LLC). Caller MUST s_waitcnt vmcnt(0) before use (rule #18).
static __device__ __forceinline__ u32x4 load_cohx4(const unsigned int* p){
  u32x4 r;
  asm volatile("global_load_dwordx4 %0, %1, off sc0 sc1"
               : "=&v"(r) : "v"(p) : "memory");
  return r;
}

// ---- workspace layout (bytes) ----
static constexpr size_t XF_OFF    = 0;
static constexpr size_t XF_SZ     = (size_t)TC_*2*12*3*64*16;      // x A-frags (triple)
static constexpr size_t WF_OFF    = XF_OFF + XF_SZ;
static constexpr size_t WF_SZ     = (size_t)32*4*28*3*64*16;       // [W;U] B-frags (triple, gate-interleaved)
static constexpr size_t WPF_OFF   = WF_OFF + WF_SZ;
static constexpr size_t WPF_SZ    = (size_t)7*16*3*64*16;          // W_proj B-frags
static constexpr size_t ZX_OFF    = WPF_OFF + WPF_SZ;
static constexpr size_t ZX_SZ     = (size_t)TC_*2*2048*16*4;       // zxT[(tl,bg)][oc][row] f32 (bias folded)
static constexpr size_t HC01_OFF  = ZX_OFF + ZX_SZ;
static constexpr size_t HC01_SZ   = (size_t)TC_*2*16*512*4;        // h planes 0|1 packed u32
static constexpr size_t HG_OFF    = HC01_OFF + HC01_SZ;
static constexpr size_t HG_SZ     = (size_t)3*2*16*2*256*4;        // h exchange ring (frag layout)
static constexpr size_t CST_OFF   = HG_OFF + HG_SZ;
static constexpr size_t CST_SZ    = (size_t)B_*H_*4;               // c state f32
static constexpr size_t FLG_OFF   = CST_OFF + CST_SZ;
static constexpr size_t FLG_SZ    = (size_t)T_*2*128*4;            // per-(step,bg,wave) publish flags

// ---------------- P1: per-chunk x A-frags (obs MLP f64-accum + action embed, triple-split) ----------------
__global__ __launch_bounds__(256) void k_prep_x(
    const float* __restrict__ obs, const float* __restrict__ act,
    const float* __restrict__ Wobs, const float* __restrict__ bobs,
    const float* __restrict__ Wact, const float* __restrict__ bact,
    u32x4* __restrict__ Xf, int tbase)
{
  __shared__ float Wl[64][257];
  __shared__ float ol[32][64];
  __shared__ float xr[32][256];
  __shared__ float al[32];
  __shared__ float wal[100], bal[100], bol[256];
  int tl = blockIdx.x; int t = tbase + tl; int tid = threadIdx.x;
  for (int i = tid; i < 64*256; i += 256) Wl[i>>8][i&255] = Wobs[i];
  for (int i = tid; i < 32*64; i += 256)
    ol[i>>6][i&63] = obs[((size_t)(i>>6)*T_ + t)*OBS_ + (i&63)];
  if (tid < 32) al[tid] = act[(size_t)tid*T_ + t];
  if (tid < 100) { wal[tid] = Wact[tid]; bal[tid] = bact[tid]; }
  bol[tid] = bobs[tid];
  __syncthreads();
  {
    int k = tid;
    double accd[32];
#pragma unroll
    for (int r = 0; r < 32; ++r) accd[r] = 0.0;
    for (int kc = 0; kc < 64; kc += 8) {
      float w[8];
#pragma unroll
      for (int q = 0; q < 8; ++q) w[q] = Wl[kc+q][k];
#pragma unroll
      for (int r = 0; r < 32; ++r) {
#pragma unroll
        for (int q = 0; q < 8; ++q) accd[r] += (double)w[q]*(double)ol[r][kc+q];
      }
    }
#pragma unroll
    for (int r = 0; r < 32; ++r) xr[r][k] = fmaxf((float)(accd[r] + (double)bol[k]), 0.f);
  }
  __syncthreads();
  int g = tid >> 6, l = tid & 63;
  int r = l & 15, sub = l >> 4;
  for (int p = g; p < 24; p += 4) {
    int bg = p / 12, kk = p % 12;
    int b = bg*16 + r;
    unsigned short vh[8], vm[8], vl[8];
#pragma unroll
    for (int j = 0; j < 8; ++j) {
      int k = kk*32 + sub*8 + j;
      float x;
      if (k < 256)      x = xr[b][k];
      else if (k < 356) {
        double tmp = (double)al[b]*(double)wal[k-256] + (double)bal[k-256];
        x = fmaxf((float)tmp, 0.f);
      } else            x = 0.f;
      split3(x, vh[j], vm[j], vl[j]);
    }
    size_t base = ((((size_t)tl*2 + bg)*12 + kk)*3)*64 + l;
    Xf[base]       = pack8(vh);
    Xf[base + 64]  = pack8(vm);
    Xf[base + 128] = pack8(vl);
  }
}

// ---------------- P2: combined [W_lstm; U_lstm] B-frags, triple-split, GATE-INTERLEAVED cols ----------------
__global__ __launch_bounds__(256) void k_prep_w(
    const float* __restrict__ Wl, const float* __restrict__ Ul,
    unsigned short* __restrict__ Wf)
{
  size_t gid = (size_t)blockIdx.x*256 + threadIdx.x;
  if (gid >= (size_t)896*2048) return;
  int k = (int)(gid >> 11), oc = (int)(gid & 2047);
  float v = 0.f;
  if (k < 356) v = Wl[(size_t)k*2048 + oc];
  else if (k >= 384) v = Ul[(size_t)(k-384)*2048 + oc];
  unsigned short vh, vm, vlo;
  split3(v, vh, vm, vlo);
  int g = oc >> 9, hu = oc & 511;
  int hs = hu >> 4, wv = (hu >> 2) & 3, u = hu & 3;
  int cc = g*4 + u;
  int kk = k >> 5, sub = (k >> 3) & 3, j = k & 7;
  size_t e = ((((size_t)(hs*4 + wv)*28 + kk)*3 + 0)*64 + (sub*16 + cc))*8 + j;
  Wf[e]        = vh;
  Wf[e + 512]  = vm;
  Wf[e + 1024] = vlo;
}

// ---------------- P3: W_proj B-frags, triple-split, cols padded to 112 ----------------
__global__ __launch_bounds__(256) void k_prep_wp(
    const float* __restrict__ Wp, unsigned short* __restrict__ Wpf)
{
  int gid = blockIdx.x*256 + threadIdx.x;
  if (gid >= 512*112) return;
  int k = gid / 112, c = gid % 112;
  float v = (c < 100) ? Wp[(size_t)k*100 + c] : 0.f;
  unsigned short vh, vm, vlo;
  split3(v, vh, vm, vlo);
  int ct = c >> 4, cl = c & 15;
  int kk = k >> 5, sub = (k >> 3) & 3, j = k & 7;
  size_t e = (((size_t)(ct*16 + kk)*3 + 0)*64 + (sub*16 + cl))*8 + j;
  Wpf[e]        = vh;
  Wpf[e + 512]  = vm;
  Wpf[e + 1024] = vlo;
}

// ---------------- P4: zxT = x-side gate preactivation + bias (transposed: [oc][row]) ----------------
__global__ __launch_bounds__(256) void k_prep_zx(
    const u32x4* __restrict__ Xf, const u32x4* __restrict__ Wf,
    const float* __restrict__ blstm, float* __restrict__ zxT)
{
  int bid = blockIdx.x;
  int hq = bid & 7, bg = (bid >> 3) & 1, tl = bid >> 4;
  int tid = threadIdx.x;
  int v = tid >> 6, lane = tid & 63;
  int cc = lane & 15; int g = cc >> 2, u = cc & 3;
  int rbase = (lane >> 4) * 4;
  u32x4 xa[12][3];
  const u32x4* xp = Xf + (((size_t)tl*2 + bg)*12*3)*64 + lane;
#pragma unroll
  for (int f = 0; f < 12; ++f)
#pragma unroll
    for (int p = 0; p < 3; ++p) xa[f][p] = xp[(f*3+p)*64];
  for (int hi = 0; hi < 4; ++hi) {
    int hs = hq*4 + hi;
    const u32x4* bp = Wf + (((size_t)(hs*4 + v)*28)*3)*64 + lane;
    f32x4 a0={0,0,0,0},a1={0,0,0,0},a2={0,0,0,0},a3={0,0,0,0},a4={0,0,0,0},a5={0,0,0,0};
#pragma unroll
    for (int f = 0; f < 12; ++f) {
      u32x4 b0 = bp[(f*3+0)*64], b1 = bp[(f*3+1)*64], b2 = bp[(f*3+2)*64];
      a0 = __builtin_amdgcn_mfma_f32_16x16x32_bf16(as_b(xa[f][0]), as_b(b0), a0, 0,0,0);
      a1 = __builtin_amdgcn_mfma_f32_16x16x32_bf16(as_b(xa[f][0]), as_b(b1), a1, 0,0,0);
      a2 = __builtin_amdgcn_mfma_f32_16x16x32_bf16(as_b(xa[f][1]), as_b(b0), a2, 0,0,0);
      a3 = __builtin_amdgcn_mfma_f32_16x16x32_bf16(as_b(xa[f][0]), as_b(b2), a3, 0,0,0);
      a4 = __builtin_amdgcn_mfma_f32_16x16x32_bf16(as_b(xa[f][2]), as_b(b0), a4, 0,0,0);
      a5 = __builtin_amdgcn_mfma_f32_16x16x32_bf16(as_b(xa[f][1]), as_b(b1), a5, 0,0,0);
    }
    int oc = g*512 + hs*16 + v*4 + u;
    double bb = (double)blstm[oc];
    f32x4 st;
#pragma unroll
    for (int q = 0; q < 4; ++q) {
      double z = (((double)a3[q]+(double)a4[q])+(double)a5[q])
               + ((double)a1[q]+(double)a2[q]) + (double)a0[q] + bb;
      st[q] = (float)z;
    }
    *(f32x4*)(zxT + ((size_t)((size_t)(tl*2 + bg)*2048 + oc))*16 + rbase) = st;
  }
}

// ---------------- R: persistent LSTM — wave-autonomous, flag-based sync, resident weights ----------------
// grid 64 = 2 bg x 32 hs; 4 waves; wave wv: all 4 gates x units hs*16+wv*4..+3 x 16 rows
__global__ __launch_bounds__(256, 1) void k_rnn(
    const u32x4* __restrict__ Wf, const float* __restrict__ zxT,
    unsigned int* __restrict__ HC01,
    unsigned int* __restrict__ hg32, unsigned int* __restrict__ flags,
    float* __restrict__ cstate, int tbase)
{
  int wg = blockIdx.x, bg = wg >> 5, hs = wg & 31;
  int tid = threadIdx.x, wv = tid >> 6, lane = tid & 63;
  int cc = lane & 15;
  int g = cc >> 2, u = cc & 3;
  int rbase = (lane >> 4) * 4;
  int U = hs*16 + wv*4 + u;
  // resident U-side weights: 32 x u32x4 = 128 VGPR (planes 0,1 only; 2^-16 terms dropped)
  u32x4 Breg[16][2];
  {
    const u32x4* bp = Wf + ((((size_t)(hs*4 + wv)*28) + 12)*3)*64 + lane;
#pragma unroll
    for (int f = 0; f < 16; ++f)
#pragma unroll
      for (int p = 0; p < 2; ++p) Breg[f][p] = bp[(f*3+p)*64];
  }
  float c[4];
#pragma unroll
  for (int q = 0; q < 4; ++q)
    c[q] = cstate[(size_t)(bg*16 + rbase + q)*512 + U];
  // ring writer mapping (lanes g==0 && u even write; cover unit pair U,U+1)
  int Ue = hs*16 + wv*4 + (u & 2);
  int wkk = Ue >> 5, wsub = (Ue >> 3) & 3, wwrd = (Ue >> 1) & 3;
  int fslot = hs*4 + wv;

#pragma unroll 1
  for (int tl = 0; tl < TC_; ++tl) {
    int gt = tbase + tl;
    // pin weights live EVERY iteration — blocks rematerialization (round-5 lesson)
#pragma unroll
    for (int f = 0; f < 16; ++f)
      asm volatile("" : "+v"(Breg[f][0]), "+v"(Breg[f][1]));
    // --- wait until all 128 waves of this bg published h(gt-1) ---
    if (gt > 0) {
      const unsigned int* fb = flags + ((size_t)(gt-1)*2 + bg)*128;
      unsigned int f0, f1;
      do {
        asm volatile("global_load_dword %0, %2, off sc0 sc1\n\t"
                     "global_load_dword %1, %3, off sc0 sc1\n\t"
                     "s_waitcnt vmcnt(0)"
                     : "=&v"(f0), "=&v"(f1)
                     : "v"(fb + lane), "v"(fb + 64 + lane) : "memory");
      } while (!__all(f0 && f1));
    }
    // --- h frags from ring slot gt-1 (agent-coherent; volatile asms keep order after poll) ---
    u32x4 hf0[16], hf1[16];
    {
      const unsigned int* hbase = hg32 + ((size_t)((gt+2)%3)*2 + bg)*16*2*256 + lane*4;
#pragma unroll
      for (int kk = 0; kk < 16; ++kk) {
        hf0[kk] = load_cohx4(hbase + (kk*2+0)*256);
        hf1[kk] = load_cohx4(hbase + (kk*2+1)*256);
      }
    }
    // --- own zx (x-side preact + bias), 4 rows contiguous ---
    f32x4 zx = *(const f32x4*)(zxT + ((size_t)((size_t)(tl*2 + bg)*2048 + g*512 + U))*16 + rbase);
    // rule #18: drain inline-asm loads and pin order before consumers
    asm volatile("s_waitcnt vmcnt(0)" ::: "memory");
    __builtin_amdgcn_sched_barrier(0);
    // --- h @ U : 3 plane-product chains, 48 MFMA ---
    f32x4 a0={0,0,0,0},a1={0,0,0,0},a2={0,0,0,0};
#pragma unroll
    for (int kk = 0; kk < 16; ++kk) {
      a0 = __builtin_amdgcn_mfma_f32_16x16x32_bf16(as_b(hf0[kk]), as_b(Breg[kk][0]), a0, 0,0,0);
      a1 = __builtin_amdgcn_mfma_f32_16x16x32_bf16(as_b(hf0[kk]), as_b(Breg[kk][1]), a1, 0,0,0);
      a2 = __builtin_amdgcn_mfma_f32_16x16x32_bf16(as_b(hf1[kk]), as_b(Breg[kk][0]), a2, 0,0,0);
    }
    // --- gates: gather 4 gates via xor-shuffles, f32 nonlinearities ---
    float hv[4];
#pragma unroll
    for (int q = 0; q < 4; ++q) {
      float z = (a1[q] + a2[q]) + a0[q] + zx[q];
      float o0 = __shfl_xor(z, 4, 64);
      float e0 = (g & 1) ? o0 : z;    // z_{g&~1}
      float e1 = (g & 1) ? z  : o0;   // z_{g|1}
      float p0 = __shfl_xor(e0, 8, 64);
      float p1 = __shfl_xor(e1, 8, 64);
      float zi = (g & 2) ? p0 : e0;
      float zf = (g & 2) ? p1 : e1;
      float zg = (g & 2) ? e0 : p0;
      float zo = (g & 2) ? e1 : p1;
      float i_ = 1.f/(1.f + expf(-zi));
      float f_ = 1.f/(1.f + expf(-zf));
      float g_ = tanhf(zg);
      float o_ = 1.f/(1.f + expf(-zo));
      c[q] = f_*c[q] + i_*g_;
      hv[q] = o_*tanhf(c[q]);
    }
    // --- pack + publish (2 planes) ---
    unsigned int* ringW = hg32 + ((size_t)(gt%3)*2 + bg)*16*2*256;
#pragma unroll
    for (int q = 0; q < 4; ++q) {
      float hq = hv[q];
      float hp = __shfl_xor(hq, 1, 64);          // partner unit (u^1)
      unsigned short h0o = f2bf(hq);
      unsigned short h1o = f2bf(hq - bf2f(h0o));
      if (g == 0) {
        size_t hcidx = ((size_t)(tl*2 + bg)*16 + rbase + q)*512 + U;
        HC01[hcidx] = (unsigned)h0o | ((unsigned)h1o << 16);
        if (!(u & 1)) {
          unsigned short h0p = f2bf(hp);
          unsigned short h1p = f2bf(hp - bf2f(h0p));
          unsigned int w0 = (unsigned)h0o | ((unsigned)h0p << 16);
          unsigned int w1 = (unsigned)h1o | ((unsigned)h1p << 16);
          size_t d0 = ((size_t)wkk*2 + 0)*256 + (wsub*16 + rbase + q)*4 + wwrd;
          __hip_atomic_store(&ringW[d0],       w0, __ATOMIC_RELAXED, __HIP_MEMORY_SCOPE_AGENT);
          __hip_atomic_store(&ringW[d0 + 256], w1, __ATOMIC_RELAXED, __HIP_MEMORY_SCOPE_AGENT);
        }
      }
    }
    // --- drain data stores, then raise this wave's flag (fire-and-forget) ---
    asm volatile("s_waitcnt vmcnt(0)" ::: "memory");
    if (lane == 0) {
      unsigned int* fp = flags + ((size_t)gt*2 + bg)*128 + fslot;
      __hip_atomic_store(fp, 1u, __ATOMIC_RELAXED, __HIP_MEMORY_SCOPE_AGENT);
    }
  }
#pragma unroll
  for (int q = 0; q < 4; ++q)
    if (g == 0) cstate[(size_t)(bg*16 + rbase + q)*512 + U] = c[q];
}

// ---------------- L: logits + softmax(pi) for one chunk (2-plane h, 3 chains) ----------------
__global__ __launch_bounds__(256) void k_logits(
    const unsigned int* __restrict__ HC01,
    const u32x4* __restrict__ Wpf,
    const float* __restrict__ bproj, float* __restrict__ out, int tbase)
{
  __shared__ float zl[16][120];
  int bid = blockIdx.x;
  int tl = bid >> 1, bg = bid & 1;
  int tid = threadIdx.x;
  int w = tid >> 6, lane = tid & 63;
  int row = lane & 15, koff = (lane >> 4) * 8;
  u32x4 a[16][2];
  {
    const unsigned int* h01 = HC01 + (((size_t)tl*2 + bg)*16 + row)*512 + koff;
#pragma unroll
    for (int kk = 0; kk < 16; ++kk) {
      u32x4 c0 = *(const u32x4*)(h01 + 32*kk);
      u32x4 c1 = *(const u32x4*)(h01 + 32*kk + 4);
      u32x4 p0, p1;
      p0.x = (c0.x & 0xffffu) | (c0.y << 16);
      p0.y = (c0.z & 0xffffu) | (c0.w << 16);
      p0.z = (c1.x & 0xffffu) | (c1.y << 16);
      p0.w = (c1.z & 0xffffu) | (c1.w << 16);
      p1.x = (c0.x >> 16) | (c0.y & 0xffff0000u);
      p1.y = (c0.z >> 16) | (c0.w & 0xffff0000u);
      p1.z = (c1.x >> 16) | (c1.y & 0xffff0000u);
      p1.w = (c1.z >> 16) | (c1.w & 0xffff0000u);
      a[kk][0] = p0;
      a[kk][1] = p1;
    }
  }
  for (int ct = w; ct < 7; ct += 4) {
    f32x4 c0 = {0,0,0,0}, c1 = {0,0,0,0}, c2 = {0,0,0,0};
    const u32x4* bp2 = Wpf + ((size_t)ct*16*3)*64 + lane;
#pragma unroll
    for (int kk = 0; kk < 16; ++kk) {
      u32x4 b0 = bp2[(kk*3+0)*64], b1 = bp2[(kk*3+1)*64];
      c0 = __builtin_amdgcn_mfma_f32_16x16x32_bf16(as_b(a[kk][0]), as_b(b0), c0, 0,0,0);
      c1 = __builtin_amdgcn_mfma_f32_16x16x32_bf16(as_b(a[kk][0]), as_b(b1), c1, 0,0,0);
      c2 = __builtin_amdgcn_mfma_f32_16x16x32_bf16(as_b(a[kk][1]), as_b(b0), c2, 0,0,0);
    }
    int col = ct*16 + (lane & 15);
    float bv = (col < 100) ? bproj[col] : 0.f;
#pragma unroll
    for (int q = 0; q < 4; ++q) {
      double z = ((double)c1[q] + (double)c2[q]) + (double)c0[q] + (double)bv;
      if (col < 120) zl[(lane>>4)*4 + q][col] = (float)z;
    }
  }
  __syncthreads();
  int srow = tid >> 4, l16 = tid & 15;
  float vv[7];
  float m = -1e30f;
#pragma unroll
  for (int k2 = 0; k2 < 7; ++k2) {
    int col = l16 + 16*k2;
    vv[k2] = (col < 100) ? zl[srow][col] : -1e30f;
    m = fmaxf(m, vv[k2]);
  }
#pragma unroll
  for (int d = 1; d < 16; d <<= 1) m = fmaxf(m, __shfl_xor(m, d, 64));
  float s = 0.f; float ek[7];
#pragma unroll
  for (int k2 = 0; k2 < 7; ++k2) {
    int col = l16 + 16*k2;
    ek[k2] = (col < 100) ? expf(vv[k2] - m) : 0.f;
    s += ek[k2];
  }
#pragma unroll
  for (int d = 1; d < 16; d <<= 1) s += __shfl_xor(s, d, 64);
  int t = tbase + tl; int b = bg*16 + srow;
  float* piout = out;
  float* lgout = out + 6553600ull;
#pragma unroll
  for (int k2 = 0; k2 < 7; ++k2) {
    int col = l16 + 16*k2;
    if (col < 100) {
      size_t idx = ((size_t)b*T_ + t)*100 + col;
      lgout[idx] = vv[k2];
      piout[idx] = ek[k2] / s;
    }
  }
}

// ---------------- A: argmax over batch axis (first-max semantics) ----------------
__global__ __launch_bounds__(128) void k_argmax(
    const float* __restrict__ lg, float* __restrict__ outA)
{
  int t = blockIdx.x, j = threadIdx.x;
  if (j >= 100) return;
  float best = lg[(size_t)t*100 + j];
  int bi = 0;
  for (int b = 1; b < 32; ++b) {
    float v = lg[((size_t)b*T_ + t)*100 + j];
    if (v > best) { best = v; bi = b; }
  }
  outA[(size_t)t*100 + j] = (float)bi;
}

extern "C" void kernel_launch(void* const* d_in, const int* in_sizes, int n_in,
                              void* d_out, int out_size, void* d_ws, size_t ws_size,
                              hipStream_t stream) {
  const float* obs  = (const float*)d_in[0];
  const float* act  = (const float*)d_in[1];
  const float* Wobs = (const float*)d_in[2];
  const float* bobs = (const float*)d_in[3];
  const float* Wact = (const float*)d_in[4];
  const float* bact = (const float*)d_in[5];
  const float* Wl   = (const float*)d_in[6];
  const float* Ul   = (const float*)d_in[7];
  const float* bl   = (const float*)d_in[8];
  const float* Wp   = (const float*)d_in[9];
  const float* bp   = (const float*)d_in[10];
  char* ws = (char*)d_ws;
  u32x4* Xf             = (u32x4*)(ws + XF_OFF);
  unsigned short* WfS   = (unsigned short*)(ws + WF_OFF);
  unsigned short* WpfS  = (unsigned short*)(ws + WPF_OFF);
  float* zxT            = (float*)(ws + ZX_OFF);
  unsigned int* HC01    = (unsigned int*)(ws + HC01_OFF);
  unsigned int* hg32    = (unsigned int*)(ws + HG_OFF);
  float* cstate         = (float*)(ws + CST_OFF);
  unsigned int* flags   = (unsigned int*)(ws + FLG_OFF);
  float* out = (float*)d_out;

  // zero exchange ring + c-state + flags each launch (replay determinism)
  hipMemsetAsync(ws + HG_OFF, 0, HG_SZ + CST_SZ + FLG_SZ, stream);
  k_prep_w<<<7168, 256, 0, stream>>>(Wl, Ul, WfS);
  k_prep_wp<<<(512*112 + 255)/256, 256, 0, stream>>>(Wp, WpfS);
  for (int ch = 0; ch < NCH_; ++ch) {
    int tb = ch * TC_;
    k_prep_x<<<TC_, 256, 0, stream>>>(obs, act, Wobs, bobs, Wact, bact, Xf, tb);
    k_prep_zx<<<TC_*2*8, 256, 0, stream>>>((const u32x4*)Xf, (const u32x4*)WfS, bl, zxT);
    k_rnn<<<64, 256, 0, stream>>>((const u32x4*)WfS, zxT, HC01,
                                  hg32, flags, cstate, tb);
    k_logits<<<TC_*2, 256, 0, stream>>>(HC01, (const u32x4*)WpfS, bp, out, tb);
  }
  k_argmax<<<T_, 128, 0, stream>>>(out + 6553600ull, out + 13107200ull);
}

// Round 7
// 14640.178 us; speedup vs baseline: 1.0738x; 1.0738x over previous
//
#include <hip/hip_runtime.h>
#include <cstdint>
#include <cstddef>

#define B_   32
#define T_   2048
#define OBS_ 64
#define FC_  256
#define ACT_ 100
#define H_   512
#define TC_  128
#define NCH_ 16

typedef __attribute__((ext_vector_type(4))) unsigned int u32x4;
typedef __attribute__((ext_vector_type(8))) short bf16x8;
typedef __attribute__((ext_vector_type(4))) float f32x4;

static __device__ __forceinline__ bf16x8 as_b(u32x4 v){ union{u32x4 u; bf16x8 b;} x; x.u=v; return x.b; }
static __device__ __forceinline__ unsigned short f2bf(float f){
  unsigned int u = __builtin_bit_cast(unsigned int, f);
  return (unsigned short)((u + 0x7fffu + ((u>>16)&1u)) >> 16);
}
static __device__ __forceinline__ float bf2f(unsigned short s){
  unsigned int u = ((unsigned int)s) << 16;
  return __builtin_bit_cast(float, u);
}
static __device__ __forceinline__ void split3(float v, unsigned short& h, unsigned short& m, unsigned short& l){
  h = f2bf(v);
  float r1 = v - bf2f(h);
  m = f2bf(r1);
  float r2 = r1 - bf2f(m);
  l = f2bf(r2);
}
static __device__ __forceinline__ u32x4 pack8(const unsigned short* v){
  u32x4 r;
  r.x = (unsigned)v[0] | ((unsigned)v[1]<<16);
  r.y = (unsigned)v[2] | ((unsigned)v[3]<<16);
  r.z = (unsigned)v[4] | ((unsigned)v[5]<<16);
  r.w = (unsigned)v[6] | ((unsigned)v[7]<<16);
  return r;
}
// agent-coherent 16B load (LLC). Caller MUST s_waitcnt vmcnt(0) before use (rule #18).
static __device__ __forceinline__ u32x4 load_cohx4(const unsigned int* p){
  u32x4 r;
  asm volatile("global_load_dwordx4 %0, %1, off sc0 sc1"
               : "=&v"(r) : "v"(p) : "memory");
  return r;
}

// ---- workspace layout (bytes) ----
static constexpr size_t XF_OFF    = 0;
static constexpr size_t XF_SZ     = (size_t)TC_*2*12*3*64*16;      // x A-frags (triple)
static constexpr size_t WF_OFF    = XF_OFF + XF_SZ;
static constexpr size_t WF_SZ     = (size_t)32*4*28*3*64*16;       // [W;U] B-frags (triple, gate-interleaved)
static constexpr size_t WPF_OFF   = WF_OFF + WF_SZ;
static constexpr size_t WPF_SZ    = (size_t)7*16*3*64*16;          // W_proj B-frags
static constexpr size_t ZX_OFF    = WPF_OFF + WPF_SZ;
static constexpr size_t ZX_SZ     = (size_t)TC_*2*2048*16*4;       // zxT[(tl,bg)][oc][row] f32 (bias folded)
static constexpr size_t HC01_OFF  = ZX_OFF + ZX_SZ;
static constexpr size_t HC01_SZ   = (size_t)TC_*2*16*512*4;        // h planes 0|1 packed u32
static constexpr size_t HG_OFF    = HC01_OFF + HC01_SZ;
static constexpr size_t HG_SZ     = (size_t)3*2*16*2*256*4;        // h exchange ring (frag layout)
static constexpr size_t CST_OFF   = HG_OFF + HG_SZ;
static constexpr size_t CST_SZ    = (size_t)B_*H_*4;               // c state f32
static constexpr size_t CTR_OFF   = CST_OFF + CST_SZ;
static constexpr size_t CTR_SZ    = (size_t)2*T_*4;                // per-(bg,step) arrival counters

// ---------------- P1: per-chunk x A-frags (obs MLP f64-accum + action embed, triple-split) ----------------
__global__ __launch_bounds__(256) void k_prep_x(
    const float* __restrict__ obs, const float* __restrict__ act,
    const float* __restrict__ Wobs, const float* __restrict__ bobs,
    const float* __restrict__ Wact, const float* __restrict__ bact,
    u32x4* __restrict__ Xf, int tbase)
{
  __shared__ float Wl[64][257];
  __shared__ float ol[32][64];
  __shared__ float xr[32][256];
  __shared__ float al[32];
  __shared__ float wal[100], bal[100], bol[256];
  int tl = blockIdx.x; int t = tbase + tl; int tid = threadIdx.x;
  for (int i = tid; i < 64*256; i += 256) Wl[i>>8][i&255] = Wobs[i];
  for (int i = tid; i < 32*64; i += 256)
    ol[i>>6][i&63] = obs[((size_t)(i>>6)*T_ + t)*OBS_ + (i&63)];
  if (tid < 32) al[tid] = act[(size_t)tid*T_ + t];
  if (tid < 100) { wal[tid] = Wact[tid]; bal[tid] = bact[tid]; }
  bol[tid] = bobs[tid];
  __syncthreads();
  {
    int k = tid;
    double accd[32];
#pragma unroll
    for (int r = 0; r < 32; ++r) accd[r] = 0.0;
    for (int kc = 0; kc < 64; kc += 8) {
      float w[8];
#pragma unroll
      for (int q = 0; q < 8; ++q) w[q] = Wl[kc+q][k];
#pragma unroll
      for (int r = 0; r < 32; ++r) {
#pragma unroll
        for (int q = 0; q < 8; ++q) accd[r] += (double)w[q]*(double)ol[r][kc+q];
      }
    }
#pragma unroll
    for (int r = 0; r < 32; ++r) xr[r][k] = fmaxf((float)(accd[r] + (double)bol[k]), 0.f);
  }
  __syncthreads();
  int g = tid >> 6, l = tid & 63;
  int r = l & 15, sub = l >> 4;
  for (int p = g; p < 24; p += 4) {
    int bg = p / 12, kk = p % 12;
    int b = bg*16 + r;
    unsigned short vh[8], vm[8], vl[8];
#pragma unroll
    for (int j = 0; j < 8; ++j) {
      int k = kk*32 + sub*8 + j;
      float x;
      if (k < 256)      x = xr[b][k];
      else if (k < 356) {
        double tmp = (double)al[b]*(double)wal[k-256] + (double)bal[k-256];
        x = fmaxf((float)tmp, 0.f);
      } else            x = 0.f;
      split3(x, vh[j], vm[j], vl[j]);
    }
    size_t base = ((((size_t)tl*2 + bg)*12 + kk)*3)*64 + l;
    Xf[base]       = pack8(vh);
    Xf[base + 64]  = pack8(vm);
    Xf[base + 128] = pack8(vl);
  }
}

// ---------------- P2: combined [W_lstm; U_lstm] B-frags, triple-split, GATE-INTERLEAVED cols ----------------
__global__ __launch_bounds__(256) void k_prep_w(
    const float* __restrict__ Wl, const float* __restrict__ Ul,
    unsigned short* __restrict__ Wf)
{
  size_t gid = (size_t)blockIdx.x*256 + threadIdx.x;
  if (gid >= (size_t)896*2048) return;
  int k = (int)(gid >> 11), oc = (int)(gid & 2047);
  float v = 0.f;
  if (k < 356) v = Wl[(size_t)k*2048 + oc];
  else if (k >= 384) v = Ul[(size_t)(k-384)*2048 + oc];
  unsigned short vh, vm, vlo;
  split3(v, vh, vm, vlo);
  int g = oc >> 9, hu = oc & 511;
  int hs = hu >> 4, wv = (hu >> 2) & 3, u = hu & 3;
  int cc = g*4 + u;
  int kk = k >> 5, sub = (k >> 3) & 3, j = k & 7;
  size_t e = ((((size_t)(hs*4 + wv)*28 + kk)*3 + 0)*64 + (sub*16 + cc))*8 + j;
  Wf[e]        = vh;
  Wf[e + 512]  = vm;
  Wf[e + 1024] = vlo;
}

// ---------------- P3: W_proj B-frags, triple-split, cols padded to 112 ----------------
__global__ __launch_bounds__(256) void k_prep_wp(
    const float* __restrict__ Wp, unsigned short* __restrict__ Wpf)
{
  int gid = blockIdx.x*256 + threadIdx.x;
  if (gid >= 512*112) return;
  int k = gid / 112, c = gid % 112;
  float v = (c < 100) ? Wp[(size_t)k*100 + c] : 0.f;
  unsigned short vh, vm, vlo;
  split3(v, vh, vm, vlo);
  int ct = c >> 4, cl = c & 15;
  int kk = k >> 5, sub = (k >> 3) & 3, j = k & 7;
  size_t e = (((size_t)(ct*16 + kk)*3 + 0)*64 + (sub*16 + cl))*8 + j;
  Wpf[e]        = vh;
  Wpf[e + 512]  = vm;
  Wpf[e + 1024] = vlo;
}

// ---------------- P4: zxT = x-side gate preactivation + bias (transposed: [oc][row]) ----------------
__global__ __launch_bounds__(256) void k_prep_zx(
    const u32x4* __restrict__ Xf, const u32x4* __restrict__ Wf,
    const float* __restrict__ blstm, float* __restrict__ zxT)
{
  int bid = blockIdx.x;
  int hq = bid & 7, bg = (bid >> 3) & 1, tl = bid >> 4;
  int tid = threadIdx.x;
  int v = tid >> 6, lane = tid & 63;
  int cc = lane & 15; int g = cc >> 2, u = cc & 3;
  int rbase = (lane >> 4) * 4;
  u32x4 xa[12][3];
  const u32x4* xp = Xf + (((size_t)tl*2 + bg)*12*3)*64 + lane;
#pragma unroll
  for (int f = 0; f < 12; ++f)
#pragma unroll
    for (int p = 0; p < 3; ++p) xa[f][p] = xp[(f*3+p)*64];
  for (int hi = 0; hi < 4; ++hi) {
    int hs = hq*4 + hi;
    const u32x4* bp = Wf + (((size_t)(hs*4 + v)*28)*3)*64 + lane;
    f32x4 a0={0,0,0,0},a1={0,0,0,0},a2={0,0,0,0},a3={0,0,0,0},a4={0,0,0,0},a5={0,0,0,0};
#pragma unroll
    for (int f = 0; f < 12; ++f) {
      u32x4 b0 = bp[(f*3+0)*64], b1 = bp[(f*3+1)*64], b2 = bp[(f*3+2)*64];
      a0 = __builtin_amdgcn_mfma_f32_16x16x32_bf16(as_b(xa[f][0]), as_b(b0), a0, 0,0,0);
      a1 = __builtin_amdgcn_mfma_f32_16x16x32_bf16(as_b(xa[f][0]), as_b(b1), a1, 0,0,0);
      a2 = __builtin_amdgcn_mfma_f32_16x16x32_bf16(as_b(xa[f][1]), as_b(b0), a2, 0,0,0);
      a3 = __builtin_amdgcn_mfma_f32_16x16x32_bf16(as_b(xa[f][0]), as_b(b2), a3, 0,0,0);
      a4 = __builtin_amdgcn_mfma_f32_16x16x32_bf16(as_b(xa[f][2]), as_b(b0), a4, 0,0,0);
      a5 = __builtin_amdgcn_mfma_f32_16x16x32_bf16(as_b(xa[f][1]), as_b(b1), a5, 0,0,0);
    }
    int oc = g*512 + hs*16 + v*4 + u;
    double bb = (double)blstm[oc];
    f32x4 st;
#pragma unroll
    for (int q = 0; q < 4; ++q) {
      double z = (((double)a3[q]+(double)a4[q])+(double)a5[q])
               + ((double)a1[q]+(double)a2[q]) + (double)a0[q] + bb;
      st[q] = (float)z;
    }
    *(f32x4*)(zxT + ((size_t)((size_t)(tl*2 + bg)*2048 + oc))*16 + rbase) = st;
  }
}

// ---------------- R: persistent LSTM — all-lane spin, single counter line, streamed weights ----------------
// grid 64 = 2 bg x 32 hs; 4 waves; wave wv: all 4 gates x units hs*16+wv*4..+3 x 16 rows
__global__ __launch_bounds__(256, 1) void k_rnn(
    const u32x4* __restrict__ Wf, const float* __restrict__ zxT,
    unsigned int* __restrict__ HC01,
    unsigned int* __restrict__ hg32, int* __restrict__ ctr,
    float* __restrict__ cstate, int tbase)
{
  int wg = blockIdx.x, bg = wg >> 5, hs = wg & 31;
  int tid = threadIdx.x, wv = tid >> 6, lane = tid & 63;
  int cc = lane & 15;
  int g = cc >> 2, u = cc & 3;
  int rbase = (lane >> 4) * 4;
  int U = hs*16 + wv*4 + u;
  // U-side weight base (streamed from L2 each step; allocator refuses residency — accept)
  const u32x4* bp = Wf + ((((size_t)(hs*4 + wv)*28) + 12)*3)*64 + lane;
  float c[4];
#pragma unroll
  for (int q = 0; q < 4; ++q)
    c[q] = cstate[(size_t)(bg*16 + rbase + q)*512 + U];
  // ring writer mapping (lanes g==0 && u even write; cover unit pair U,U+1)
  int Ue = hs*16 + wv*4 + (u & 2);
  int wkk = Ue >> 5, wsub = (Ue >> 3) & 3, wwrd = (Ue >> 1) & 3;

#pragma unroll 1
  for (int tl = 0; tl < TC_; ++tl) {
    int gt = tbase + tl;
    // --- zx prefetch (independent of recurrence; completes during spin) ---
    f32x4 zx = *(const f32x4*)(zxT + ((size_t)((size_t)(tl*2 + bg)*2048 + g*512 + U))*16 + rbase);
    // --- all-lane spin: step gt-1 fully published (32 WG arrivals) ---
    if (tl > 0) {
      const int* cp = ctr + ((size_t)bg*T_ + (gt-1));
      int cv;
      for (;;) {
        asm volatile("global_load_dword %0, %1, off sc0 sc1\n\t"
                     "s_waitcnt vmcnt(0)"
                     : "=&v"(cv) : "v"(cp) : "memory");
        if (cv >= 32) break;
        __builtin_amdgcn_s_sleep(1);
      }
    }
    // --- h frags from ring slot gt-1 (agent-coherent) ---
    u32x4 hf0[16], hf1[16];
    {
      const unsigned int* hbase = hg32 + ((size_t)((gt+2)%3)*2 + bg)*16*2*256 + lane*4;
#pragma unroll
      for (int kk = 0; kk < 16; ++kk) {
        hf0[kk] = load_cohx4(hbase + (kk*2+0)*256);
        hf1[kk] = load_cohx4(hbase + (kk*2+1)*256);
      }
    }
    // rule #18: drain inline-asm loads and pin order before consumers
    asm volatile("s_waitcnt vmcnt(0)" ::: "memory");
    __builtin_amdgcn_sched_barrier(0);
    // --- h @ U : 3 plane-product chains, 48 MFMA; weights streamed (L2-warm) ---
    f32x4 a0={0,0,0,0},a1={0,0,0,0},a2={0,0,0,0};
#pragma unroll
    for (int kk = 0; kk < 16; ++kk) {
      u32x4 b0 = bp[(kk*3+0)*64], b1 = bp[(kk*3+1)*64];
      a0 = __builtin_amdgcn_mfma_f32_16x16x32_bf16(as_b(hf0[kk]), as_b(b0), a0, 0,0,0);
      a1 = __builtin_amdgcn_mfma_f32_16x16x32_bf16(as_b(hf0[kk]), as_b(b1), a1, 0,0,0);
      a2 = __builtin_amdgcn_mfma_f32_16x16x32_bf16(as_b(hf1[kk]), as_b(b0), a2, 0,0,0);
    }
    // --- gates: gather 4 gates via xor-shuffles, f32 nonlinearities ---
    float hv[4];
#pragma unroll
    for (int q = 0; q < 4; ++q) {
      float z = (a1[q] + a2[q]) + a0[q] + zx[q];
      float o0 = __shfl_xor(z, 4, 64);
      float e0 = (g & 1) ? o0 : z;    // z_{g&~1}
      float e1 = (g & 1) ? z  : o0;   // z_{g|1}
      float p0 = __shfl_xor(e0, 8, 64);
      float p1 = __shfl_xor(e1, 8, 64);
      float zi = (g & 2) ? p0 : e0;
      float zf = (g & 2) ? p1 : e1;
      float zg = (g & 2) ? e0 : p0;
      float zo = (g & 2) ? e1 : p1;
      float i_ = 1.f/(1.f + expf(-zi));
      float f_ = 1.f/(1.f + expf(-zf));
      float g_ = tanhf(zg);
      float o_ = 1.f/(1.f + expf(-zo));
      c[q] = f_*c[q] + i_*g_;
      hv[q] = o_*tanhf(c[q]);
    }
    // --- pack + publish (2 planes) ---
    unsigned int* ringW = hg32 + ((size_t)(gt%3)*2 + bg)*16*2*256;
#pragma unroll
    for (int q = 0; q < 4; ++q) {
      float hq = hv[q];
      float hp = __shfl_xor(hq, 1, 64);          // partner unit (u^1)
      unsigned short h0o = f2bf(hq);
      unsigned short h1o = f2bf(hq - bf2f(h0o));
      if (g == 0) {
        size_t hcidx = ((size_t)(tl*2 + bg)*16 + rbase + q)*512 + U;
        HC01[hcidx] = (unsigned)h0o | ((unsigned)h1o << 16);
        if (!(u & 1)) {
          unsigned short h0p = f2bf(hp);
          unsigned short h1p = f2bf(hp - bf2f(h0p));
          unsigned int w0 = (unsigned)h0o | ((unsigned)h0p << 16);
          unsigned int w1 = (unsigned)h1o | ((unsigned)h1p << 16);
          size_t d0 = ((size_t)wkk*2 + 0)*256 + (wsub*16 + rbase + q)*4 + wwrd;
          __hip_atomic_store(&ringW[d0],       w0, __ATOMIC_RELAXED, __HIP_MEMORY_SCOPE_AGENT);
          __hip_atomic_store(&ringW[d0 + 256], w1, __ATOMIC_RELAXED, __HIP_MEMORY_SCOPE_AGENT);
        }
      }
    }
    // --- arrive: WG-wide store drain via s_barrier, then ONE add per WG ---
    if (tl < TC_-1) {
      __syncthreads();   // drains all 4 waves' stores (vmcnt) before the arrive
      if (tid == 0)
        __hip_atomic_fetch_add(&ctr[(size_t)bg*T_ + gt], 1, __ATOMIC_RELAXED, __HIP_MEMORY_SCOPE_AGENT);
      // no release barrier: next iteration's all-lane spin is the release
    }
  }
#pragma unroll
  for (int q = 0; q < 4; ++q)
    if (g == 0) cstate[(size_t)(bg*16 + rbase + q)*512 + U] = c[q];
}

// ---------------- L: logits + softmax(pi) for one chunk (2-plane h, 3 chains) ----------------
__global__ __launch_bounds__(256) void k_logits(
    const unsigned int* __restrict__ HC01,
    const u32x4* __restrict__ Wpf,
    const float* __restrict__ bproj, float* __restrict__ out, int tbase)
{
  __shared__ float zl[16][120];
  int bid = blockIdx.x;
  int tl = bid >> 1, bg = bid & 1;
  int tid = threadIdx.x;
  int w = tid >> 6, lane = tid & 63;
  int row = lane & 15, koff = (lane >> 4) * 8;
  u32x4 a[16][2];
  {
    const unsigned int* h01 = HC01 + (((size_t)tl*2 + bg)*16 + row)*512 + koff;
#pragma unroll
    for (int kk = 0; kk < 16; ++kk) {
      u32x4 c0 = *(const u32x4*)(h01 + 32*kk);
      u32x4 c1 = *(const u32x4*)(h01 + 32*kk + 4);
      u32x4 p0, p1;
      p0.x = (c0.x & 0xffffu) | (c0.y << 16);
      p0.y = (c0.z & 0xffffu) | (c0.w << 16);
      p0.z = (c1.x & 0xffffu) | (c1.y << 16);
      p0.w = (c1.z & 0xffffu) | (c1.w << 16);
      p1.x = (c0.x >> 16) | (c0.y & 0xffff0000u);
      p1.y = (c0.z >> 16) | (c0.w & 0xffff0000u);
      p1.z = (c1.x >> 16) | (c1.y & 0xffff0000u);
      p1.w = (c1.z >> 16) | (c1.w & 0xffff0000u);
      a[kk][0] = p0;
      a[kk][1] = p1;
    }
  }
  for (int ct = w; ct < 7; ct += 4) {
    f32x4 c0 = {0,0,0,0}, c1 = {0,0,0,0}, c2 = {0,0,0,0};
    const u32x4* bp2 = Wpf + ((size_t)ct*16*3)*64 + lane;
#pragma unroll
    for (int kk = 0; kk < 16; ++kk) {
      u32x4 b0 = bp2[(kk*3+0)*64], b1 = bp2[(kk*3+1)*64];
      c0 = __builtin_amdgcn_mfma_f32_16x16x32_bf16(as_b(a[kk][0]), as_b(b0), c0, 0,0,0);
      c1 = __builtin_amdgcn_mfma_f32_16x16x32_bf16(as_b(a[kk][0]), as_b(b1), c1, 0,0,0);
      c2 = __builtin_amdgcn_mfma_f32_16x16x32_bf16(as_b(a[kk][1]), as_b(b0), c2, 0,0,0);
    }
    int col = ct*16 + (lane & 15);
    float bv = (col < 100) ? bproj[col] : 0.f;
#pragma unroll
    for (int q = 0; q < 4; ++q) {
      double z = ((double)c1[q] + (double)c2[q]) + (double)c0[q] + (double)bv;
      if (col < 120) zl[(lane>>4)*4 + q][col] = (float)z;
    }
  }
  __syncthreads();
  int srow = tid >> 4, l16 = tid & 15;
  float vv[7];
  float m = -1e30f;
#pragma unroll
  for (int k2 = 0; k2 < 7; ++k2) {
    int col = l16 + 16*k2;
    vv[k2] = (col < 100) ? zl[srow][col] : -1e30f;
    m = fmaxf(m, vv[k2]);
  }
#pragma unroll
  for (int d = 1; d < 16; d <<= 1) m = fmaxf(m, __shfl_xor(m, d, 64));
  float s = 0.f; float ek[7];
#pragma unroll
  for (int k2 = 0; k2 < 7; ++k2) {
    int col = l16 + 16*k2;
    ek[k2] = (col < 100) ? expf(vv[k2] - m) : 0.f;
    s += ek[k2];
  }
#pragma unroll
  for (int d = 1; d < 16; d <<= 1) s += __shfl_xor(s, d, 64);
  int t = tbase + tl; int b = bg*16 + srow;
  float* piout = out;
  float* lgout = out + 6553600ull;
#pragma unroll
  for (int k2 = 0; k2 < 7; ++k2) {
    int col = l16 + 16*k2;
    if (col < 100) {
      size_t idx = ((size_t)b*T_ + t)*100 + col;
      lgout[idx] = vv[k2];
      piout[idx] = ek[k2] / s;
    }
  }
}

// ---------------- A: argmax over batch axis (first-max semantics) ----------------
__global__ __launch_bounds__(128) void k_argmax(
    const float* __restrict__ lg, float* __restrict__ outA)
{
  int t = blockIdx.x, j = threadIdx.x;
  if (j >= 100) return;
  float best = lg[(size_t)t*100 + j];
  int bi = 0;
  for (int b = 1; b < 32; ++b) {
    float v = lg[((size_t)b*T_ + t)*100 + j];
    if (v > best) { best = v; bi = b; }
  }
  outA[(size_t)t*100 + j] = (float)bi;
}

extern "C" void kernel_launch(void* const* d_in, const int* in_sizes, int n_in,
                              void* d_out, int out_size, void* d_ws, size_t ws_size,
                              hipStream_t stream) {
  const float* obs  = (const float*)d_in[0];
  const float* act  = (const float*)d_in[1];
  const float* Wobs = (const float*)d_in[2];
  const float* bobs = (const float*)d_in[3];
  const float* Wact = (const float*)d_in[4];
  const float* bact = (const float*)d_in[5];
  const float* Wl   = (const float*)d_in[6];
  const float* Ul   = (const float*)d_in[7];
  const float* bl   = (const float*)d_in[8];
  const float* Wp   = (const float*)d_in[9];
  const float* bp   = (const float*)d_in[10];
  char* ws = (char*)d_ws;
  u32x4* Xf             = (u32x4*)(ws + XF_OFF);
  unsigned short* WfS   = (unsigned short*)(ws + WF_OFF);
  unsigned short* WpfS  = (unsigned short*)(ws + WPF_OFF);
  float* zxT            = (float*)(ws + ZX_OFF);
  unsigned int* HC01    = (unsigned int*)(ws + HC01_OFF);
  unsigned int* hg32    = (unsigned int*)(ws + HG_OFF);
  float* cstate         = (float*)(ws + CST_OFF);
  int* ctr              = (int*)(ws + CTR_OFF);
  float* out = (float*)d_out;

  // zero exchange ring + c-state + counters each launch (replay determinism)
  hipMemsetAsync(ws + HG_OFF, 0, HG_SZ + CST_SZ + CTR_SZ, stream);
  k_prep_w<<<7168, 256, 0, stream>>>(Wl, Ul, WfS);
  k_prep_wp<<<(512*112 + 255)/256, 256, 0, stream>>>(Wp, WpfS);
  for (int ch = 0; ch < NCH_; ++ch) {
    int tb = ch * TC_;
    k_prep_x<<<TC_, 256, 0, stream>>>(obs, act, Wobs, bobs, Wact, bact, Xf, tb);
    k_prep_zx<<<TC_*2*8, 256, 0, stream>>>((const u32x4*)Xf, (const u32x4*)WfS, bl, zxT);
    k_rnn<<<64, 256, 0, stream>>>((const u32x4*)WfS, zxT, HC01,
                                  hg32, ctr, cstate, tb);
    k_logits<<<TC_*2, 256, 0, stream>>>(HC01, (const u32x4*)WpfS, bp, out, tb);
  }
  k_argmax<<<T_, 128, 0, stream>>>(out + 6553600ull, out + 13107200ull);
}

// Round 8
// 12499.377 us; speedup vs baseline: 1.2577x; 1.1713x over previous
//
#include <hip/hip_runtime.h>
#include <cstdint>
#include <cstddef>

#define B_   32
#define T_   2048
#define OBS_ 64
#define FC_  256
#define ACT_ 100
#define H_   512
#define TC_  128
#define NCH_ 16

typedef __attribute__((ext_vector_type(4))) unsigned int u32x4;
typedef __attribute__((ext_vector_type(8))) short bf16x8;
typedef __attribute__((ext_vector_type(4))) float f32x4;

static __device__ __forceinline__ bf16x8 as_b(u32x4 v){ union{u32x4 u; bf16x8 b;} x; x.u=v; return x.b; }
static __device__ __forceinline__ unsigned short f2bf(float f){
  unsigned int u = __builtin_bit_cast(unsigned int, f);
  return (unsigned short)((u + 0x7fffu + ((u>>16)&1u)) >> 16);
}
static __device__ __forceinline__ float bf2f(unsigned short s){
  unsigned int u = ((unsigned int)s) << 16;
  return __builtin_bit_cast(float, u);
}
static __device__ __forceinline__ void split3(float v, unsigned short& h, unsigned short& m, unsigned short& l){
  h = f2bf(v);
  float r1 = v - bf2f(h);
  m = f2bf(r1);
  float r2 = r1 - bf2f(m);
  l = f2bf(r2);
}
static __device__ __forceinline__ u32x4 pack8(const unsigned short* v){
  u32x4 r;
  r.x = (unsigned)v[0] | ((unsigned)v[1]<<16);
  r.y = (unsigned)v[2] | ((unsigned)v[3]<<16);
  r.z = (unsigned)v[4] | ((unsigned)v[5]<<16);
  r.w = (unsigned)v[6] | ((unsigned)v[7]<<16);
  return r;
}
// agent-coherent 16B load (LLC). Caller MUST s_waitcnt vmcnt(0) before use (rule #18).
static __device__ __forceinline__ u32x4 load_cohx4(const unsigned int* p){
  u32x4 r;
  asm volatile("global_load_dwordx4 %0, %1, off sc0 sc1"
               : "=&v"(r) : "v"(p) : "memory");
  return r;
}

// ---- workspace layout (bytes) ----
static constexpr size_t XF_OFF    = 0;
static constexpr size_t XF_SZ     = (size_t)TC_*2*12*3*64*16;      // x A-frags (triple)
static constexpr size_t WF_OFF    = XF_OFF + XF_SZ;
static constexpr size_t WF_SZ     = (size_t)32*4*28*3*64*16;       // [W;U] B-frags (triple, gate-interleaved)
static constexpr size_t WPF_OFF   = WF_OFF + WF_SZ;
static constexpr size_t WPF_SZ    = (size_t)7*16*3*64*16;          // W_proj B-frags
static constexpr size_t ZX_OFF    = WPF_OFF + WPF_SZ;
static constexpr size_t ZX_SZ     = (size_t)TC_*2*2048*16*4;       // zxT[(tl,bg)][oc][row] f32 (bias folded)
static constexpr size_t HC01_OFF  = ZX_OFF + ZX_SZ;
static constexpr size_t HC01_SZ   = (size_t)TC_*2*16*512*4;        // h planes 0|1 packed u32
static constexpr size_t HG_OFF    = HC01_OFF + HC01_SZ;
static constexpr size_t HG_SZ     = (size_t)3*2*16*2*256*4;        // h exchange ring (frag layout)
static constexpr size_t CST_OFF   = HG_OFF + HG_SZ;
static constexpr size_t CST_SZ    = (size_t)B_*H_*4;               // c state f32
static constexpr size_t CTR_OFF   = CST_OFF + CST_SZ;
static constexpr size_t CTR_SZ    = (size_t)2*T_*4;                // per-(bg,step) arrival counters

// ---------------- P1: per-chunk x A-frags (obs MLP f64-accum + action embed, triple-split) ----------------
__global__ __launch_bounds__(256) void k_prep_x(
    const float* __restrict__ obs, const float* __restrict__ act,
    const float* __restrict__ Wobs, const float* __restrict__ bobs,
    const float* __restrict__ Wact, const float* __restrict__ bact,
    u32x4* __restrict__ Xf, int tbase)
{
  __shared__ float Wl[64][257];
  __shared__ float ol[32][64];
  __shared__ float xr[32][256];
  __shared__ float al[32];
  __shared__ float wal[100], bal[100], bol[256];
  int tl = blockIdx.x; int t = tbase + tl; int tid = threadIdx.x;
  for (int i = tid; i < 64*256; i += 256) Wl[i>>8][i&255] = Wobs[i];
  for (int i = tid; i < 32*64; i += 256)
    ol[i>>6][i&63] = obs[((size_t)(i>>6)*T_ + t)*OBS_ + (i&63)];
  if (tid < 32) al[tid] = act[(size_t)tid*T_ + t];
  if (tid < 100) { wal[tid] = Wact[tid]; bal[tid] = bact[tid]; }
  bol[tid] = bobs[tid];
  __syncthreads();
  {
    int k = tid;
    double accd[32];
#pragma unroll
    for (int r = 0; r < 32; ++r) accd[r] = 0.0;
    for (int kc = 0; kc < 64; kc += 8) {
      float w[8];
#pragma unroll
      for (int q = 0; q < 8; ++q) w[q] = Wl[kc+q][k];
#pragma unroll
      for (int r = 0; r < 32; ++r) {
#pragma unroll
        for (int q = 0; q < 8; ++q) accd[r] += (double)w[q]*(double)ol[r][kc+q];
      }
    }
#pragma unroll
    for (int r = 0; r < 32; ++r) xr[r][k] = fmaxf((float)(accd[r] + (double)bol[k]), 0.f);
  }
  __syncthreads();
  int g = tid >> 6, l = tid & 63;
  int r = l & 15, sub = l >> 4;
  for (int p = g; p < 24; p += 4) {
    int bg = p / 12, kk = p % 12;
    int b = bg*16 + r;
    unsigned short vh[8], vm[8], vl[8];
#pragma unroll
    for (int j = 0; j < 8; ++j) {
      int k = kk*32 + sub*8 + j;
      float x;
      if (k < 256)      x = xr[b][k];
      else if (k < 356) {
        double tmp = (double)al[b]*(double)wal[k-256] + (double)bal[k-256];
        x = fmaxf((float)tmp, 0.f);
      } else            x = 0.f;
      split3(x, vh[j], vm[j], vl[j]);
    }
    size_t base = ((((size_t)tl*2 + bg)*12 + kk)*3)*64 + l;
    Xf[base]       = pack8(vh);
    Xf[base + 64]  = pack8(vm);
    Xf[base + 128] = pack8(vl);
  }
}

// ---------------- P2: combined [W_lstm; U_lstm] B-frags, triple-split, GATE-INTERLEAVED cols ----------------
__global__ __launch_bounds__(256) void k_prep_w(
    const float* __restrict__ Wl, const float* __restrict__ Ul,
    unsigned short* __restrict__ Wf)
{
  size_t gid = (size_t)blockIdx.x*256 + threadIdx.x;
  if (gid >= (size_t)896*2048) return;
  int k = (int)(gid >> 11), oc = (int)(gid & 2047);
  float v = 0.f;
  if (k < 356) v = Wl[(size_t)k*2048 + oc];
  else if (k >= 384) v = Ul[(size_t)(k-384)*2048 + oc];
  unsigned short vh, vm, vlo;
  split3(v, vh, vm, vlo);
  int g = oc >> 9, hu = oc & 511;
  int hs = hu >> 4, wv = (hu >> 2) & 3, u = hu & 3;
  int cc = g*4 + u;
  int kk = k >> 5, sub = (k >> 3) & 3, j = k & 7;
  size_t e = ((((size_t)(hs*4 + wv)*28 + kk)*3 + 0)*64 + (sub*16 + cc))*8 + j;
  Wf[e]        = vh;
  Wf[e + 512]  = vm;
  Wf[e + 1024] = vlo;
}

// ---------------- P3: W_proj B-frags, triple-split, cols padded to 112 ----------------
__global__ __launch_bounds__(256) void k_prep_wp(
    const float* __restrict__ Wp, unsigned short* __restrict__ Wpf)
{
  int gid = blockIdx.x*256 + threadIdx.x;
  if (gid >= 512*112) return;
  int k = gid / 112, c = gid % 112;
  float v = (c < 100) ? Wp[(size_t)k*100 + c] : 0.f;
  unsigned short vh, vm, vlo;
  split3(v, vh, vm, vlo);
  int ct = c >> 4, cl = c & 15;
  int kk = k >> 5, sub = (k >> 3) & 3, j = k & 7;
  size_t e = (((size_t)(ct*16 + kk)*3 + 0)*64 + (sub*16 + cl))*8 + j;
  Wpf[e]        = vh;
  Wpf[e + 512]  = vm;
  Wpf[e + 1024] = vlo;
}

// ---------------- P4: zxT = x-side gate preactivation + bias (transposed: [oc][row]) ----------------
__global__ __launch_bounds__(256) void k_prep_zx(
    const u32x4* __restrict__ Xf, const u32x4* __restrict__ Wf,
    const float* __restrict__ blstm, float* __restrict__ zxT)
{
  int bid = blockIdx.x;
  int hq = bid & 7, bg = (bid >> 3) & 1, tl = bid >> 4;
  int tid = threadIdx.x;
  int v = tid >> 6, lane = tid & 63;
  int cc = lane & 15; int g = cc >> 2, u = cc & 3;
  int rbase = (lane >> 4) * 4;
  u32x4 xa[12][3];
  const u32x4* xp = Xf + (((size_t)tl*2 + bg)*12*3)*64 + lane;
#pragma unroll
  for (int f = 0; f < 12; ++f)
#pragma unroll
    for (int p = 0; p < 3; ++p) xa[f][p] = xp[(f*3+p)*64];
  for (int hi = 0; hi < 4; ++hi) {
    int hs = hq*4 + hi;
    const u32x4* bp = Wf + (((size_t)(hs*4 + v)*28)*3)*64 + lane;
    f32x4 a0={0,0,0,0},a1={0,0,0,0},a2={0,0,0,0},a3={0,0,0,0},a4={0,0,0,0},a5={0,0,0,0};
#pragma unroll
    for (int f = 0; f < 12; ++f) {
      u32x4 b0 = bp[(f*3+0)*64], b1 = bp[(f*3+1)*64], b2 = bp[(f*3+2)*64];
      a0 = __builtin_amdgcn_mfma_f32_16x16x32_bf16(as_b(xa[f][0]), as_b(b0), a0, 0,0,0);
      a1 = __builtin_amdgcn_mfma_f32_16x16x32_bf16(as_b(xa[f][0]), as_b(b1), a1, 0,0,0);
      a2 = __builtin_amdgcn_mfma_f32_16x16x32_bf16(as_b(xa[f][1]), as_b(b0), a2, 0,0,0);
      a3 = __builtin_amdgcn_mfma_f32_16x16x32_bf16(as_b(xa[f][0]), as_b(b2), a3, 0,0,0);
      a4 = __builtin_amdgcn_mfma_f32_16x16x32_bf16(as_b(xa[f][2]), as_b(b0), a4, 0,0,0);
      a5 = __builtin_amdgcn_mfma_f32_16x16x32_bf16(as_b(xa[f][1]), as_b(b1), a5, 0,0,0);
    }
    int oc = g*512 + hs*16 + v*4 + u;
    double bb = (double)blstm[oc];
    f32x4 st;
#pragma unroll
    for (int q = 0; q < 4; ++q) {
      double z = (((double)a3[q]+(double)a4[q])+(double)a5[q])
               + ((double)a1[q]+(double)a2[q]) + (double)a0[q] + bb;
      st[q] = (float)z;
    }
    *(f32x4*)(zxT + ((size_t)((size_t)(tl*2 + bg)*2048 + oc))*16 + rbase) = st;
  }
}

// ---------------- R: persistent LSTM — r3 sync skeleton + weight prefetch under the spin ----------------
// grid 64 = 2 bg x 32 hs; 4 waves; wave wv: all 4 gates x units hs*16+wv*4..+3 x 16 rows
__global__ __launch_bounds__(256, 1) void k_rnn(
    const u32x4* __restrict__ Wf, const float* __restrict__ zxT,
    unsigned int* __restrict__ HC01,
    unsigned int* __restrict__ hg32, int* __restrict__ ctr,
    float* __restrict__ cstate, int tbase)
{
  int wg = blockIdx.x, bg = wg >> 5, hs = wg & 31;
  int tid = threadIdx.x, wv = tid >> 6, lane = tid & 63;
  int cc = lane & 15;
  int g = cc >> 2, u = cc & 3;
  int rbase = (lane >> 4) * 4;
  int U = hs*16 + wv*4 + u;
  const u32x4* bp = Wf + ((((size_t)(hs*4 + wv)*28) + 12)*3)*64 + lane;
  float c[4];
#pragma unroll
  for (int q = 0; q < 4; ++q)
    c[q] = cstate[(size_t)(bg*16 + rbase + q)*512 + U];
  // ring writer mapping (lanes g==0 && u even write; cover unit pair U,U+1)
  int Ue = hs*16 + wv*4 + (u & 2);
  int wkk = Ue >> 5, wsub = (Ue >> 3) & 3, wwrd = (Ue >> 1) & 3;

  // initial prefetch: weights (loop-invariant) + zx for tl=0. The h-independent
  // loads are issued BEFORE each wait so their L2 latency hides under the spin.
  u32x4 wa[16], wb[16];
#pragma unroll
  for (int kk = 0; kk < 16; ++kk) { wa[kk] = bp[(kk*3+0)*64]; wb[kk] = bp[(kk*3+1)*64]; }
  f32x4 zx = *(const f32x4*)(zxT + ((size_t)((size_t)(0*2 + bg)*2048 + g*512 + U))*16 + rbase);

#pragma unroll 1
  for (int tl = 0; tl < TC_; ++tl) {
    int gt = tbase + tl;
    // --- wait for h(gt-1): tid0-only spin (minimal pollers on the hot line), barrier releases ---
    if (tl > 0) {
      if (tid == 0) {
        const int* cp = ctr + ((size_t)bg*T_ + (gt-1));
        int cv;
        for (;;) {
          asm volatile("global_load_dword %0, %1, off sc0 sc1\n\t"
                       "s_waitcnt vmcnt(0)"
                       : "=&v"(cv) : "v"(cp) : "memory");
          if (cv >= 32) break;
          __builtin_amdgcn_s_sleep(1);
        }
      }
      __syncthreads();
    }
    // --- h frags from ring slot gt-1 (agent-coherent) ---
    u32x4 hf0[16], hf1[16];
    {
      const unsigned int* hbase = hg32 + ((size_t)((gt+2)%3)*2 + bg)*16*2*256 + lane*4;
#pragma unroll
      for (int kk = 0; kk < 16; ++kk) {
        hf0[kk] = load_cohx4(hbase + (kk*2+0)*256);
        hf1[kk] = load_cohx4(hbase + (kk*2+1)*256);
      }
    }
    // rule #18: drain inline-asm loads and pin order before consumers
    asm volatile("s_waitcnt vmcnt(0)" ::: "memory");
    __builtin_amdgcn_sched_barrier(0);
    // --- h @ U : 3 plane-product chains, 48 MFMA; weights already in registers ---
    f32x4 a0={0,0,0,0},a1={0,0,0,0},a2={0,0,0,0};
#pragma unroll
    for (int kk = 0; kk < 16; ++kk) {
      a0 = __builtin_amdgcn_mfma_f32_16x16x32_bf16(as_b(hf0[kk]), as_b(wa[kk]), a0, 0,0,0);
      a1 = __builtin_amdgcn_mfma_f32_16x16x32_bf16(as_b(hf0[kk]), as_b(wb[kk]), a1, 0,0,0);
      a2 = __builtin_amdgcn_mfma_f32_16x16x32_bf16(as_b(hf1[kk]), as_b(wa[kk]), a2, 0,0,0);
    }
    // --- gates: gather 4 gates via xor-shuffles, f32 nonlinearities ---
    float hv[4];
#pragma unroll
    for (int q = 0; q < 4; ++q) {
      float z = (a1[q] + a2[q]) + a0[q] + zx[q];
      float o0 = __shfl_xor(z, 4, 64);
      float e0 = (g & 1) ? o0 : z;    // z_{g&~1}
      float e1 = (g & 1) ? z  : o0;   // z_{g|1}
      float p0 = __shfl_xor(e0, 8, 64);
      float p1 = __shfl_xor(e1, 8, 64);
      float zi = (g & 2) ? p0 : e0;
      float zf = (g & 2) ? p1 : e1;
      float zg = (g & 2) ? e0 : p0;
      float zo = (g & 2) ? e1 : p1;
      float i_ = 1.f/(1.f + expf(-zi));
      float f_ = 1.f/(1.f + expf(-zf));
      float g_ = tanhf(zg);
      float o_ = 1.f/(1.f + expf(-zo));
      c[q] = f_*c[q] + i_*g_;
      hv[q] = o_*tanhf(c[q]);
    }
    // --- pack + publish (2 planes) ---
    unsigned int* ringW = hg32 + ((size_t)(gt%3)*2 + bg)*16*2*256;
#pragma unroll
    for (int q = 0; q < 4; ++q) {
      float hq = hv[q];
      float hp = __shfl_xor(hq, 1, 64);          // partner unit (u^1)
      unsigned short h0o = f2bf(hq);
      unsigned short h1o = f2bf(hq - bf2f(h0o));
      if (g == 0) {
        size_t hcidx = ((size_t)(tl*2 + bg)*16 + rbase + q)*512 + U;
        HC01[hcidx] = (unsigned)h0o | ((unsigned)h1o << 16);
        if (!(u & 1)) {
          unsigned short h0p = f2bf(hp);
          unsigned short h1p = f2bf(hp - bf2f(h0p));
          unsigned int w0 = (unsigned)h0o | ((unsigned)h0p << 16);
          unsigned int w1 = (unsigned)h1o | ((unsigned)h1p << 16);
          size_t d0 = ((size_t)wkk*2 + 0)*256 + (wsub*16 + rbase + q)*4 + wwrd;
          __hip_atomic_store(&ringW[d0],       w0, __ATOMIC_RELAXED, __HIP_MEMORY_SCOPE_AGENT);
          __hip_atomic_store(&ringW[d0 + 256], w1, __ATOMIC_RELAXED, __HIP_MEMORY_SCOPE_AGENT);
        }
      }
    }
    // --- drain (WG-wide), arrive, then prefetch next step's h-independent inputs ---
    if (tl < TC_-1) {
      __syncthreads();   // drains all 4 waves' stores (vmcnt) before the arrive
      if (tid == 0)
        __hip_atomic_fetch_add(&ctr[(size_t)bg*T_ + gt], 1, __ATOMIC_RELAXED, __HIP_MEMORY_SCOPE_AGENT);
      // prefetch for tl+1: in flight while the barrier completes / spin runs.
      // (cannot sink below the spin: its asm has a "memory" clobber.)
      zx = *(const f32x4*)(zxT + ((size_t)((size_t)((tl+1)*2 + bg)*2048 + g*512 + U))*16 + rbase);
#pragma unroll
      for (int kk = 0; kk < 16; ++kk) { wa[kk] = bp[(kk*3+0)*64]; wb[kk] = bp[(kk*3+1)*64]; }
    }
  }
#pragma unroll
  for (int q = 0; q < 4; ++q)
    if (g == 0) cstate[(size_t)(bg*16 + rbase + q)*512 + U] = c[q];
}

// ---------------- L: logits + softmax(pi) for one chunk (2-plane h, 3 chains) ----------------
__global__ __launch_bounds__(256) void k_logits(
    const unsigned int* __restrict__ HC01,
    const u32x4* __restrict__ Wpf,
    const float* __restrict__ bproj, float* __restrict__ out, int tbase)
{
  __shared__ float zl[16][120];
  int bid = blockIdx.x;
  int tl = bid >> 1, bg = bid & 1;
  int tid = threadIdx.x;
  int w = tid >> 6, lane = tid & 63;
  int row = lane & 15, koff = (lane >> 4) * 8;
  u32x4 a[16][2];
  {
    const unsigned int* h01 = HC01 + (((size_t)tl*2 + bg)*16 + row)*512 + koff;
#pragma unroll
    for (int kk = 0; kk < 16; ++kk) {
      u32x4 c0 = *(const u32x4*)(h01 + 32*kk);
      u32x4 c1 = *(const u32x4*)(h01 + 32*kk + 4);
      u32x4 p0, p1;
      p0.x = (c0.x & 0xffffu) | (c0.y << 16);
      p0.y = (c0.z & 0xffffu) | (c0.w << 16);
      p0.z = (c1.x & 0xffffu) | (c1.y << 16);
      p0.w = (c1.z & 0xffffu) | (c1.w << 16);
      p1.x = (c0.x >> 16) | (c0.y & 0xffff0000u);
      p1.y = (c0.z >> 16) | (c0.w & 0xffff0000u);
      p1.z = (c1.x >> 16) | (c1.y & 0xffff0000u);
      p1.w = (c1.z >> 16) | (c1.w & 0xffff0000u);
      a[kk][0] = p0;
      a[kk][1] = p1;
    }
  }
  for (int ct = w; ct < 7; ct += 4) {
    f32x4 c0 = {0,0,0,0}, c1 = {0,0,0,0}, c2 = {0,0,0,0};
    const u32x4* bp2 = Wpf + ((size_t)ct*16*3)*64 + lane;
#pragma unroll
    for (int kk = 0; kk < 16; ++kk) {
      u32x4 b0 = bp2[(kk*3+0)*64], b1 = bp2[(kk*3+1)*64];
      c0 = __builtin_amdgcn_mfma_f32_16x16x32_bf16(as_b(a[kk][0]), as_b(b0), c0, 0,0,0);
      c1 = __builtin_amdgcn_mfma_f32_16x16x32_bf16(as_b(a[kk][0]), as_b(b1), c1, 0,0,0);
      c2 = __builtin_amdgcn_mfma_f32_16x16x32_bf16(as_b(a[kk][1]), as_b(b0), c2, 0,0,0);
    }
    int col = ct*16 + (lane & 15);
    float bv = (col < 100) ? bproj[col] : 0.f;
#pragma unroll
    for (int q = 0; q < 4; ++q) {
      double z = ((double)c1[q] + (double)c2[q]) + (double)c0[q] + (double)bv;
      if (col < 120) zl[(lane>>4)*4 + q][col] = (float)z;
    }
  }
  __syncthreads();
  int srow = tid >> 4, l16 = tid & 15;
  float vv[7];
  float m = -1e30f;
#pragma unroll
  for (int k2 = 0; k2 < 7; ++k2) {
    int col = l16 + 16*k2;
    vv[k2] = (col < 100) ? zl[srow][col] : -1e30f;
    m = fmaxf(m, vv[k2]);
  }
#pragma unroll
  for (int d = 1; d < 16; d <<= 1) m = fmaxf(m, __shfl_xor(m, d, 64));
  float s = 0.f; float ek[7];
#pragma unroll
  for (int k2 = 0; k2 < 7; ++k2) {
    int col = l16 + 16*k2;
    ek[k2] = (col < 100) ? expf(vv[k2] - m) : 0.f;
    s += ek[k2];
  }
#pragma unroll
  for (int d = 1; d < 16; d <<= 1) s += __shfl_xor(s, d, 64);
  int t = tbase + tl; int b = bg*16 + srow;
  float* piout = out;
  float* lgout = out + 6553600ull;
#pragma unroll
  for (int k2 = 0; k2 < 7; ++k2) {
    int col = l16 + 16*k2;
    if (col < 100) {
      size_t idx = ((size_t)b*T_ + t)*100 + col;
      lgout[idx] = vv[k2];
      piout[idx] = ek[k2] / s;
    }
  }
}

// ---------------- A: argmax over batch axis (first-max semantics) ----------------
__global__ __launch_bounds__(128) void k_argmax(
    const float* __restrict__ lg, float* __restrict__ outA)
{
  int t = blockIdx.x, j = threadIdx.x;
  if (j >= 100) return;
  float best = lg[(size_t)t*100 + j];
  int bi = 0;
  for (int b = 1; b < 32; ++b) {
    float v = lg[((size_t)b*T_ + t)*100 + j];
    if (v > best) { best = v; bi = b; }
  }
  outA[(size_t)t*100 + j] = (float)bi;
}

extern "C" void kernel_launch(void* const* d_in, const int* in_sizes, int n_in,
                              void* d_out, int out_size, void* d_ws, size_t ws_size,
                              hipStream_t stream) {
  const float* obs  = (const float*)d_in[0];
  const float* act  = (const float*)d_in[1];
  const float* Wobs = (const float*)d_in[2];
  const float* bobs = (const float*)d_in[3];
  const float* Wact = (const float*)d_in[4];
  const float* bact = (const float*)d_in[5];
  const float* Wl   = (const float*)d_in[6];
  const float* Ul   = (const float*)d_in[7];
  const float* bl   = (const float*)d_in[8];
  const float* Wp   = (const float*)d_in[9];
  const float* bp   = (const float*)d_in[10];
  char* ws = (char*)d_ws;
  u32x4* Xf             = (u32x4*)(ws + XF_OFF);
  unsigned short* WfS   = (unsigned short*)(ws + WF_OFF);
  unsigned short* WpfS  = (unsigned short*)(ws + WPF_OFF);
  float* zxT            = (float*)(ws + ZX_OFF);
  unsigned int* HC01    = (unsigned int*)(ws + HC01_OFF);
  unsigned int* hg32    = (unsigned int*)(ws + HG_OFF);
  float* cstate         = (float*)(ws + CST_OFF);
  int* ctr              = (int*)(ws + CTR_OFF);
  float* out = (float*)d_out;

  // zero exchange ring + c-state + counters each launch (replay determinism)
  hipMemsetAsync(ws + HG_OFF, 0, HG_SZ + CST_SZ + CTR_SZ, stream);
  k_prep_w<<<7168, 256, 0, stream>>>(Wl, Ul, WfS);
  k_prep_wp<<<(512*112 + 255)/256, 256, 0, stream>>>(Wp, WpfS);
  for (int ch = 0; ch < NCH_; ++ch) {
    int tb = ch * TC_;
    k_prep_x<<<TC_, 256, 0, stream>>>(obs, act, Wobs, bobs, Wact, bact, Xf, tb);
    k_prep_zx<<<TC_*2*8, 256, 0, stream>>>((const u32x4*)Xf, (const u32x4*)WfS, bl, zxT);
    k_rnn<<<64, 256, 0, stream>>>((const u32x4*)WfS, zxT, HC01,
                                  hg32, ctr, cstate, tb);
    k_logits<<<TC_*2, 256, 0, stream>>>(HC01, (const u32x4*)WpfS, bp, out, tb);
  }
  k_argmax<<<T_, 128, 0, stream>>>(out + 6553600ull, out + 13107200ull);
}